// Round 1
// 533.429 us; speedup vs baseline: 1.0164x; 1.0164x over previous
//
#include <hip/hip_runtime.h>
#include <hip/hip_bf16.h>

#define NEG_SLOPE 0.2f

typedef _Float16 f16x8 __attribute__((ext_vector_type(8)));
typedef float f32x4 __attribute__((ext_vector_type(4)));
typedef unsigned short ushort_t;

#define AS_GLOBAL(p) ((const __attribute__((address_space(1))) void*)(p))
#define AS_SHARED(p) ((__attribute__((address_space(3))) void*)(p))

// ---------------------------------------------------------------------------
// CSR build: histogram of dst, parallel exclusive scan (+1 self-loop), fill
// ---------------------------------------------------------------------------

__global__ void khist(const int* __restrict__ dst, int E, int* __restrict__ counts) {
    int i = blockIdx.x * blockDim.x + threadIdx.x;
    if (i < E) atomicAdd(&counts[dst[i]], 1);
}

__global__ __launch_bounds__(1024) void kscan_part(const int* __restrict__ counts,
                                                   int* __restrict__ row_ptr,
                                                   int* __restrict__ bsum, int n) {
    __shared__ int wsum[16];
    int t = threadIdx.x, lane = t & 63, wid = t >> 6;
    int i = blockIdx.x * 1024 + t;
    int v = (i < n) ? (counts[i] + 1) : 0;
    int x = v;
    #pragma unroll
    for (int off = 1; off < 64; off <<= 1) {
        int y = __shfl_up(x, off, 64);
        if (lane >= off) x += y;
    }
    if (lane == 63) wsum[wid] = x;
    __syncthreads();
    if (wid == 0) {
        int ws = (lane < 16) ? wsum[lane] : 0;
        #pragma unroll
        for (int off = 1; off < 16; off <<= 1) {
            int y = __shfl_up(ws, off, 64);
            if (lane >= off) ws += y;
        }
        if (lane < 16) wsum[lane] = ws;
    }
    __syncthreads();
    int wave_excl = (wid == 0) ? 0 : wsum[wid - 1];
    if (i < n) row_ptr[i] = wave_excl + (x - v);
    if (t == 0) bsum[blockIdx.x] = wsum[15];
}

__global__ void kscan_tops(const int* __restrict__ bsum, int* __restrict__ boff,
                           int* __restrict__ row_ptr, int G, int n) {
    int lane = threadIdx.x;
    int v = (lane < G) ? bsum[lane] : 0;
    int x = v;
    #pragma unroll
    for (int off = 1; off < 64; off <<= 1) {
        int y = __shfl_up(x, off, 64);
        if (lane >= off) x += y;
    }
    if (lane < G) boff[lane] = x - v;
    if (lane == 63) row_ptr[n] = x;
}

__global__ void kscan_add(int* __restrict__ row_ptr, const int* __restrict__ boff,
                          int* __restrict__ cursor, int n) {
    int i = blockIdx.x * blockDim.x + threadIdx.x;
    if (i < n) {
        int r = row_ptr[i] + boff[i >> 10];
        row_ptr[i] = r;
        cursor[i] = r;
    }
}

__global__ void kfill(const int* __restrict__ src, const int* __restrict__ dst,
                      int E, int n, int* __restrict__ cursor, int* __restrict__ edge_src) {
    int i = blockIdx.x * blockDim.x + threadIdx.x;
    if (i < E) {
        int p = atomicAdd(&cursor[dst[i]], 1);
        edge_src[p] = src[i];
    } else if (i < E + n) {
        int v = i - E;
        int p = atomicAdd(&cursor[v], 1);
        edge_src[p] = v;
    }
}

// ---------------------------------------------------------------------------
// Weight prep: W_pre -> fp16 (single pass; h0 is stored fp16 so hi/lo split
// precision would be wasted), W1 -> fp16. Both swizzled to MFMA-B-frag
// order: elem (k,n) -> ((k>>3)*Nn + n)*8 + (k&7).
// ---------------------------------------------------------------------------
__global__ void kprep(const float* __restrict__ Wpre, const float* __restrict__ W1,
                      ushort_t* __restrict__ PreF, ushort_t* __restrict__ W1h) {
    int i = blockIdx.x * blockDim.x + threadIdx.x;
    if (i < 1024 * 128) {
        int k = i >> 7, n = i & 127;
        int d = ((k >> 3) * 128 + n) * 8 + (k & 7);
        PreF[d] = __builtin_bit_cast(ushort_t, (_Float16)Wpre[i]);
    } else if (i < 1024 * 128 + 128 * 256) {
        int j2 = i - 1024 * 128;
        int k = j2 >> 8, n = j2 & 255;
        int d = ((k >> 3) * 256 + n) * 8 + (k & 7);
        W1h[d] = __builtin_bit_cast(ushort_t, (_Float16)W1[j2]);
    }
}

__device__ inline f16x8 cvt8(const float* v) {
    f16x8 r;
    #pragma unroll
    for (int i = 0; i < 8; ++i) r[i] = (_Float16)v[i];
    return r;
}

// ---------------------------------------------------------------------------
// GEMM1: h0h(fp16) = relu(x @ W_pre + b_pre).  M x 1024 x 128.
// Single-pass f16 MFMA (fp32 A converted in-register), async B staging,
// A prefetched one tile ahead.
// ---------------------------------------------------------------------------
__global__ __launch_bounds__(256) void kgemm_mfma1(const float* __restrict__ A,
                                                   const ushort_t* __restrict__ Bf,
                                                   const float* __restrict__ bias,
                                                   ushort_t* __restrict__ C, int M) {
    __shared__ __align__(16) ushort_t Bs[8192];   // one K-tile: [kc8][n128][j8] fp16 = 16 KB
    int t = threadIdx.x;
    int wid = t >> 6, lane = t & 63;
    int q = lane >> 4, l15 = lane & 15;
    int m0 = blockIdx.x * 64 + wid * 16;
    int m = m0 + l15;
    const float* arow = A + (size_t)(m < M ? m : 0) * 1024;

    f32x4 acc[8];
    #pragma unroll
    for (int c = 0; c < 8; ++c) acc[c] = (f32x4){0.f, 0.f, 0.f, 0.f};

    float4 av[2][4];
    #pragma unroll
    for (int ks = 0; ks < 2; ++ks) {
        av[0][ks * 2]     = *(const float4*)(arow + ks * 32 + q * 8);
        av[0][ks * 2 + 1] = *(const float4*)(arow + ks * 32 + q * 8 + 4);
    }

    #pragma unroll 2
    for (int kt = 0; kt < 16; ++kt) {
        int cur = kt & 1, nxt = cur ^ 1;
        __syncthreads();
        {
            const ushort_t* sF = Bf + kt * 8192;
            #pragma unroll
            for (int i = 0; i < 4; ++i) {
                int ge = (i * 256 + t) * 8;
                int le = (i * 256 + (t & 0xC0)) * 8;
                __builtin_amdgcn_global_load_lds(AS_GLOBAL(sF + ge), AS_SHARED(Bs + le), 16, 0, 0);
            }
        }
        if (kt < 15) {
            const float* a2 = arow + (kt + 1) * 64;
            #pragma unroll
            for (int ks = 0; ks < 2; ++ks) {
                av[nxt][ks * 2]     = *(const float4*)(a2 + ks * 32 + q * 8);
                av[nxt][ks * 2 + 1] = *(const float4*)(a2 + ks * 32 + q * 8 + 4);
            }
        }
        __syncthreads();
        #pragma unroll
        for (int ks = 0; ks < 2; ++ks) {
            f16x8 af = cvt8((const float*)&av[cur][ks * 2]);
            int kc = ks * 4 + q;
            #pragma unroll
            for (int c = 0; c < 8; ++c) {
                f16x8 b = *(const f16x8*)(Bs + (kc * 128 + c * 16 + l15) * 8);
                acc[c] = __builtin_amdgcn_mfma_f32_16x16x32_f16(af, b, acc[c], 0, 0, 0);
            }
        }
    }
    #pragma unroll
    for (int c = 0; c < 8; ++c) {
        int n = c * 16 + l15;
        float bv = bias[n];
        #pragma unroll
        for (int r = 0; r < 4; ++r) {
            int mm = m0 + q * 4 + r;
            if (mm < M)
                C[(size_t)mm * 128 + n] =
                    __builtin_bit_cast(ushort_t, (_Float16)fmaxf(acc[c][r] + bv, 0.f));
        }
    }
}

// ---------------------------------------------------------------------------
// GEMM2 + fused alpha1: h1h(fp16) = h0h @ W1h, f16 MFMA.
// Block = 64 rows x 128 cols; g = blockIdx.y = column half = head.
// Epilogue also computes as1/ad1 for head g via in-wave reduction over the
// 16 col-lanes (cols of head g are entirely within this block).
// ---------------------------------------------------------------------------
__global__ __launch_bounds__(256) void kgemm_mfma2(const ushort_t* __restrict__ Ah,
                                                   const ushort_t* __restrict__ W1h,
                                                   const float* __restrict__ a_src,
                                                   const float* __restrict__ a_dst,
                                                   ushort_t* __restrict__ C,
                                                   float* __restrict__ as1,
                                                   float* __restrict__ ad1, int M) {
    __shared__ __align__(16) ushort_t Bs[16384];  // [kc16][n128][j8] fp16 = 32 KB
    int t = threadIdx.x;
    int wid = t >> 6, lane = t & 63;
    int q = lane >> 4, l15 = lane & 15;
    int g = blockIdx.y;
    int m0 = blockIdx.x * 64 + wid * 16;
    int m = m0 + l15;
    const ushort_t* arow = Ah + (size_t)(m < M ? m : 0) * 128;

    {   // stage W1h half (cols g*128..+127): 32 wave-chunks of 1 KB
        #pragma unroll
        for (int i = 0; i < 8; ++i) {
            int j = i * 4 + wid;
            int kc = j >> 1, hk = j & 1;
            int ge = ((kc * 256) + g * 128 + hk * 64 + lane) * 8;
            int le = j * 512;
            __builtin_amdgcn_global_load_lds(AS_GLOBAL(W1h + ge), AS_SHARED(Bs + le), 16, 0, 0);
        }
    }
    f16x8 af[4];
    #pragma unroll
    for (int ks = 0; ks < 4; ++ks)
        af[ks] = *(const f16x8*)(arow + ks * 32 + q * 8);
    __syncthreads();

    f32x4 acc[8];
    #pragma unroll
    for (int c = 0; c < 8; ++c) acc[c] = (f32x4){0.f, 0.f, 0.f, 0.f};

    #pragma unroll
    for (int ks = 0; ks < 4; ++ks) {
        int kc = ks * 4 + q;
        #pragma unroll
        for (int c = 0; c < 8; ++c) {
            f16x8 b = *(const f16x8*)(Bs + (kc * 128 + c * 16 + l15) * 8);
            acc[c] = __builtin_amdgcn_mfma_f32_16x16x32_f16(af[ks], b, acc[c], 0, 0, 0);
        }
    }
    // h1h store
    #pragma unroll
    for (int c = 0; c < 8; ++c) {
        int n = g * 128 + c * 16 + l15;
        #pragma unroll
        for (int r = 0; r < 4; ++r) {
            int mm = m0 + q * 4 + r;
            if (mm < M)
                C[(size_t)mm * 256 + n] = __builtin_bit_cast(ushort_t, (_Float16)acc[c][r]);
        }
    }
    // fused alpha: as1/ad1 for head g
    float asv[4] = {0.f, 0.f, 0.f, 0.f};
    float adv[4] = {0.f, 0.f, 0.f, 0.f};
    #pragma unroll
    for (int c = 0; c < 8; ++c) {
        float sa = a_src[g * 128 + c * 16 + l15];
        float da = a_dst[g * 128 + c * 16 + l15];
        #pragma unroll
        for (int r = 0; r < 4; ++r) {
            asv[r] += acc[c][r] * sa;
            adv[r] += acc[c][r] * da;
        }
    }
    #pragma unroll
    for (int off = 1; off <= 8; off <<= 1) {
        #pragma unroll
        for (int r = 0; r < 4; ++r) {
            asv[r] += __shfl_xor(asv[r], off, 64);
            adv[r] += __shfl_xor(adv[r], off, 64);
        }
    }
    if (l15 == 0) {
        #pragma unroll
        for (int r = 0; r < 4; ++r) {
            int node = m0 + q * 4 + r;
            if (node < M) {
                as1[node * 2 + g] = asv[r];
                ad1[node * 2 + g] = adv[r];
            }
        }
    }
}

// ---------------------------------------------------------------------------
// Aggregation layer 1 + fused layer-2 linear + alpha2.
// 128-thread block per dst node; thread t owns channels 2t,2t+1 (head t>>6).
// out1 (post-ELU) lives only in registers; block-reduces out1@W2 -> h2/as2/ad2.
// ---------------------------------------------------------------------------
__global__ __launch_bounds__(128) void kagg1(const ushort_t* __restrict__ h1h,
                                             const float* __restrict__ as1,
                                             const float* __restrict__ ad1,
                                             const float* __restrict__ b1,
                                             const float* __restrict__ W2,
                                             const float* __restrict__ a_src2,
                                             const float* __restrict__ a_dst2,
                                             const int* __restrict__ row_ptr,
                                             const int* __restrict__ edge_src,
                                             float* __restrict__ h2,
                                             float* __restrict__ as2,
                                             float* __restrict__ ad2, int n) {
    __shared__ float w_lds[128];   // [edge 64][head 2]
    __shared__ int   s_lds[64];
    __shared__ float red[2][4];
    int node = blockIdx.x;
    int t = threadIdx.x;
    int wid = t >> 6;
    int beg = row_ptr[node], end = row_ptr[node + 1];
    int h_ch = t >> 6;                      // head of my channel pair
    float advv = ad1[node * 2 + (t & 1)];   // head used in weight phase
    float acc0 = 0.f, acc1 = 0.f, ssum = 0.f;
    for (int base = beg; base < end; base += 64) {
        int cnt = min(64, end - base);
        int i = t >> 1, h = t & 1;
        if (i < cnt) {
            int s = edge_src[base + i];
            float e = as1[s * 2 + h] + advv;
            e = (e > 0.f) ? e : NEG_SLOPE * e;
            w_lds[i * 2 + h] = __expf(e);
            if (h == 0) s_lds[i] = s;
        }
        __syncthreads();
        #pragma unroll 4
        for (int i2 = 0; i2 < cnt; ++i2) {
            float wv = w_lds[i2 * 2 + h_ch];
            int s = s_lds[i2];
            unsigned p = *(const unsigned*)(h1h + (size_t)s * 256 + t * 2);
            _Float16 lo16 = __builtin_bit_cast(_Float16, (ushort_t)(p & 0xffffu));
            _Float16 hi16 = __builtin_bit_cast(_Float16, (ushort_t)(p >> 16));
            acc0 += wv * (float)lo16;
            acc1 += wv * (float)hi16;
            ssum += wv;
        }
        __syncthreads();
    }
    float inv = 1.f / (ssum + 1e-16f);
    float o0 = acc0 * inv + b1[t * 2];
    float o1 = acc1 * inv + b1[t * 2 + 1];
    o0 = (o0 > 0.f) ? o0 : (__expf(o0) - 1.f);
    o1 = (o1 > 0.f) ? o1 : (__expf(o1) - 1.f);
    // fused linear: partial[j] = o0*W2[2t][j] + o1*W2[2t+1][j]
    float4 w0 = *(const float4*)(W2 + t * 8);
    float4 w1 = *(const float4*)(W2 + t * 8 + 4);
    float p0 = o0 * w0.x + o1 * w1.x;
    float p1 = o0 * w0.y + o1 * w1.y;
    float p2 = o0 * w0.z + o1 * w1.z;
    float p3 = o0 * w0.w + o1 * w1.w;
    #pragma unroll
    for (int off = 1; off < 64; off <<= 1) {
        p0 += __shfl_xor(p0, off, 64);
        p1 += __shfl_xor(p1, off, 64);
        p2 += __shfl_xor(p2, off, 64);
        p3 += __shfl_xor(p3, off, 64);
    }
    if ((t & 63) == 0) {
        red[wid][0] = p0; red[wid][1] = p1; red[wid][2] = p2; red[wid][3] = p3;
    }
    __syncthreads();
    if (t == 0) {
        float hv[4], s2 = 0.f, d2 = 0.f;
        #pragma unroll
        for (int j = 0; j < 4; ++j) {
            hv[j] = red[0][j] + red[1][j];
            h2[node * 4 + j] = hv[j];
            s2 += hv[j] * a_src2[j];
            d2 += hv[j] * a_dst2[j];
        }
        as2[node] = s2;
        ad2[node] = d2;
    }
}

// ---------------------------------------------------------------------------
// Aggregation layer 2 (1 head, C=4): wave per node, 16 edges in flight.
// ---------------------------------------------------------------------------
__global__ __launch_bounds__(256) void kagg2(const float* __restrict__ h2,
                                             const float* __restrict__ as2,
                                             const float* __restrict__ ad2,
                                             const float* __restrict__ b2,
                                             const int* __restrict__ row_ptr,
                                             const int* __restrict__ edge_src,
                                             float* __restrict__ out, int n) {
    int wid = threadIdx.x >> 6, lane = threadIdx.x & 63;
    int node = blockIdx.x * 4 + wid;
    if (node >= n) return;
    int beg = row_ptr[node], end = row_ptr[node + 1];
    int j = lane & 3, ig = lane >> 2;
    float adv = ad2[node];
    float acc = 0.f, ssum = 0.f;
    for (int p = beg + ig; p < end; p += 16) {
        int s = edge_src[p];
        float e = as2[s] + adv;
        e = (e > 0.f) ? e : NEG_SLOPE * e;
        float wv = __expf(e);
        acc += wv * h2[s * 4 + j];
        ssum += wv;
    }
    #pragma unroll
    for (int off = 32; off >= 4; off >>= 1) {
        acc += __shfl_down(acc, off);
        ssum += __shfl_down(ssum, off);
    }
    if (lane < 4) out[node * 4 + j] = acc / (ssum + 1e-16f) + b2[j];
}

// ---------------------------------------------------------------------------
extern "C" void kernel_launch(void* const* d_in, const int* in_sizes, int n_in,
                              void* d_out, int out_size, void* d_ws, size_t ws_size,
                              hipStream_t stream) {
    const float* x      = (const float*)d_in[0];
    const int*   ei     = (const int*)d_in[1];
    const float* W_pre  = (const float*)d_in[2];
    const float* b_pre  = (const float*)d_in[3];
    const float* W1     = (const float*)d_in[4];
    const float* a_src1 = (const float*)d_in[5];
    const float* a_dst1 = (const float*)d_in[6];
    const float* b1     = (const float*)d_in[7];
    const float* W2     = (const float*)d_in[8];
    const float* a_src2 = (const float*)d_in[9];
    const float* a_dst2 = (const float*)d_in[10];
    const float* b2     = (const float*)d_in[11];
    float* out = (float*)d_out;

    const int DIN = 1024;
    const int E = in_sizes[1] / 2;
    const int N = in_sizes[0] / DIN;

    const int* esrc = ei;
    const int* edst = ei + E;

    char* ws = (char*)d_ws;
    size_t off = 0;
    ushort_t* h1h = (ushort_t*)(ws + off); off += (size_t)N * 256 * 2;  // fp16 h1
    ushort_t* h0h = (ushort_t*)(ws + off); off += (size_t)N * 128 * 2;  // fp16 h0
    float* as1 = (float*)(ws + off);  off += (size_t)N * 2 * 4;
    float* ad1 = (float*)(ws + off);  off += (size_t)N * 2 * 4;
    float* h2  = (float*)(ws + off);  off += (size_t)N * 4 * 4;
    float* as2 = (float*)(ws + off);  off += (size_t)N * 4;
    float* ad2 = (float*)(ws + off);  off += (size_t)N * 4;
    int* row_ptr = (int*)(ws + off);  off += ((size_t)N + 16) * 4;
    int* cursor  = (int*)(ws + off);  off += (size_t)N * 4;
    int* counts  = (int*)(ws + off);  off += (size_t)N * 4;
    int* bsum    = (int*)(ws + off);  off += 64 * 4;
    int* boff    = (int*)(ws + off);  off += 64 * 4;
    int* edge_src = (int*)(ws + off); off += (size_t)(E + N) * 4;
    ushort_t* PreF = (ushort_t*)(ws + off); off += 1024 * 128 * 2;
    ushort_t* W1h  = (ushort_t*)(ws + off); off += 128 * 256 * 2;

    int G = (N + 1023) / 1024;

    // --- weight prep + CSR build ---
    kprep<<<640, 256, 0, stream>>>(W_pre, W1, PreF, W1h);
    hipMemsetAsync(counts, 0, (size_t)N * 4, stream);
    khist<<<(E + 255) / 256, 256, 0, stream>>>(edst, E, counts);
    kscan_part<<<G, 1024, 0, stream>>>(counts, row_ptr, bsum, N);
    kscan_tops<<<1, 64, 0, stream>>>(bsum, boff, row_ptr, G, N);
    kscan_add<<<(N + 255) / 256, 256, 0, stream>>>(row_ptr, boff, cursor, N);
    kfill<<<(E + N + 255) / 256, 256, 0, stream>>>(esrc, edst, E, N, cursor, edge_src);

    int Mb = (N + 63) / 64;
    // --- h0h = relu(x @ W_pre + b_pre), single-pass f16 MFMA ---
    kgemm_mfma1<<<Mb, 256, 0, stream>>>(x, PreF, b_pre, h0h, N);
    // --- h1h = h0h @ W1h, + as1/ad1 fused ---
    {
        dim3 grid(Mb, 2);
        kgemm_mfma2<<<grid, 256, 0, stream>>>(h0h, W1h, a_src1, a_dst1, h1h, as1, ad1, N);
    }
    // --- aggregate layer 1 + bias + elu + layer-2 linear + alpha2 (fused) ---
    kagg1<<<N, 128, 0, stream>>>(h1h, as1, ad1, b1, W2, a_src2, a_dst2,
                                 row_ptr, edge_src, h2, as2, ad2, N);
    // --- aggregate layer 2 + bias -> out ---
    kagg2<<<(N + 3) / 4, 256, 0, stream>>>(h2, as2, ad2, b2, row_ptr, edge_src, out, N);
}

// Round 3
// 521.616 us; speedup vs baseline: 1.0394x; 1.0226x over previous
//
#include <hip/hip_runtime.h>
#include <hip/hip_bf16.h>

#define NEG_SLOPE 0.2f

typedef _Float16 f16x8 __attribute__((ext_vector_type(8)));
typedef _Float16 f16x4 __attribute__((ext_vector_type(4)));
typedef float f32x4 __attribute__((ext_vector_type(4)));
typedef unsigned short ushort_t;

#define AS_GLOBAL(p) ((const __attribute__((address_space(1))) void*)(p))
#define AS_SHARED(p) ((__attribute__((address_space(3))) void*)(p))

// ---------------------------------------------------------------------------
// CSR build: histogram of dst, parallel exclusive scan (+1 self-loop), fill
// ---------------------------------------------------------------------------

__global__ void khist(const int* __restrict__ dst, int E, int* __restrict__ counts) {
    int i = blockIdx.x * blockDim.x + threadIdx.x;
    if (i < E) atomicAdd(&counts[dst[i]], 1);
}

__global__ __launch_bounds__(1024) void kscan_part(const int* __restrict__ counts,
                                                   int* __restrict__ row_ptr,
                                                   int* __restrict__ bsum, int n) {
    __shared__ int wsum[16];
    int t = threadIdx.x, lane = t & 63, wid = t >> 6;
    int i = blockIdx.x * 1024 + t;
    int v = (i < n) ? (counts[i] + 1) : 0;
    int x = v;
    #pragma unroll
    for (int off = 1; off < 64; off <<= 1) {
        int y = __shfl_up(x, off, 64);
        if (lane >= off) x += y;
    }
    if (lane == 63) wsum[wid] = x;
    __syncthreads();
    if (wid == 0) {
        int ws = (lane < 16) ? wsum[lane] : 0;
        #pragma unroll
        for (int off = 1; off < 16; off <<= 1) {
            int y = __shfl_up(ws, off, 64);
            if (lane >= off) ws += y;
        }
        if (lane < 16) wsum[lane] = ws;
    }
    __syncthreads();
    int wave_excl = (wid == 0) ? 0 : wsum[wid - 1];
    if (i < n) row_ptr[i] = wave_excl + (x - v);
    if (t == 0) bsum[blockIdx.x] = wsum[15];
}

__global__ void kscan_tops(const int* __restrict__ bsum, int* __restrict__ boff,
                           int* __restrict__ row_ptr, int G, int n) {
    int lane = threadIdx.x;
    int v = (lane < G) ? bsum[lane] : 0;
    int x = v;
    #pragma unroll
    for (int off = 1; off < 64; off <<= 1) {
        int y = __shfl_up(x, off, 64);
        if (lane >= off) x += y;
    }
    if (lane < G) boff[lane] = x - v;
    if (lane == 63) row_ptr[n] = x;
}

__global__ void kscan_add(int* __restrict__ row_ptr, const int* __restrict__ boff,
                          int* __restrict__ cursor, int n) {
    int i = blockIdx.x * blockDim.x + threadIdx.x;
    if (i < n) {
        int r = row_ptr[i] + boff[i >> 10];
        row_ptr[i] = r;
        cursor[i] = r;
    }
}

__global__ void kfill(const int* __restrict__ src, const int* __restrict__ dst,
                      int E, int n, int* __restrict__ cursor, int* __restrict__ edge_src) {
    int i = blockIdx.x * blockDim.x + threadIdx.x;
    if (i < E) {
        int p = atomicAdd(&cursor[dst[i]], 1);
        edge_src[p] = src[i];
    } else if (i < E + n) {
        int v = i - E;
        int p = atomicAdd(&cursor[v], 1);
        edge_src[p] = v;
    }
}

// ---------------------------------------------------------------------------
// Weight prep: W_pre -> fp16, W1 -> fp16, swizzled to MFMA-B-frag order:
// elem (k,n) -> ((k>>3)*Nn + n)*8 + (k&7).
// ---------------------------------------------------------------------------
__global__ void kprep(const float* __restrict__ Wpre, const float* __restrict__ W1,
                      ushort_t* __restrict__ PreF, ushort_t* __restrict__ W1h) {
    int i = blockIdx.x * blockDim.x + threadIdx.x;
    if (i < 1024 * 128) {
        int k = i >> 7, n = i & 127;
        int d = ((k >> 3) * 128 + n) * 8 + (k & 7);
        PreF[d] = __builtin_bit_cast(ushort_t, (_Float16)Wpre[i]);
    } else if (i < 1024 * 128 + 128 * 256) {
        int j2 = i - 1024 * 128;
        int k = j2 >> 8, n = j2 & 255;
        int d = ((k >> 3) * 256 + n) * 8 + (k & 7);
        W1h[d] = __builtin_bit_cast(ushort_t, (_Float16)W1[j2]);
    }
}

__device__ inline f16x4 cvt4(float4 v) {
    f16x4 r;
    r[0] = (_Float16)v.x; r[1] = (_Float16)v.y;
    r[2] = (_Float16)v.z; r[3] = (_Float16)v.w;
    return r;
}

// ---------------------------------------------------------------------------
// GEMM1: h0h(fp16) = relu(x @ W_pre + b_pre).  M x 1024 x 128.
// M-tile 32, 4 waves = 2 row-halves x 2 col-halves. A staged cooperatively:
// coalesced float4 loads -> fp16 cvt -> XOR-swizzled LDS (chunk c of row r
// stored at chunk (c ^ (r & 7))). B via global_load_lds (pre-swizzled).
// ---------------------------------------------------------------------------
__global__ __launch_bounds__(256) void kgemm_mfma1(const float* __restrict__ A,
                                                   const ushort_t* __restrict__ Bf,
                                                   const float* __restrict__ bias,
                                                   ushort_t* __restrict__ C, int M) {
    __shared__ __align__(16) ushort_t Bs[8192];   // 16 KB: B K-tile [kc8][n128][j8]
    __shared__ __align__(16) ushort_t As[2048];   // 4 KB: A tile 32x64 fp16, swizzled
    int t = threadIdx.x;
    int wid = t >> 6, lane = t & 63, q = lane >> 4, l15 = lane & 15;
    int wr = wid & 1, wc = wid >> 1;
    int m0 = blockIdx.x * 32;

    int ar = t >> 3, ac = t & 7;
    int srow = m0 + ar;
    if (srow >= M) srow = M - 1;
    const float* sA = A + (size_t)srow * 1024;
    int sw = ar & 7;                              // write-side XOR (row mod 8)
    int wadr0 = ar * 64 + (((ac >> 1)) ^ sw) * 8 + (ac & 1) * 4;
    int wadr1 = ar * 64 + ((4 + (ac >> 1)) ^ sw) * 8 + (ac & 1) * 4;

    float4 av[2][2];
    av[0][0] = *(const float4*)(sA + ac * 4);
    av[0][1] = *(const float4*)(sA + 32 + ac * 4);

    f32x4 acc[4];
    #pragma unroll
    for (int c = 0; c < 4; ++c) acc[c] = (f32x4){0.f, 0.f, 0.f, 0.f};

    int arow_rd = (wr * 16 + l15) * 64;
    int asw = l15 & 7;                            // read-side XOR (row mod 8)

    #pragma unroll 2
    for (int kt = 0; kt < 16; ++kt) {
        int cur = kt & 1, nxt = cur ^ 1;
        __syncthreads();
        {   // B-tile kt -> LDS (async DMA)
            const ushort_t* sF = Bf + kt * 8192;
            #pragma unroll
            for (int i = 0; i < 4; ++i) {
                int ge = (i * 256 + t) * 8;
                int le = (i * 256 + (t & 0xC0)) * 8;
                __builtin_amdgcn_global_load_lds(AS_GLOBAL(sF + ge), AS_SHARED(Bs + le), 16, 0, 0);
            }
        }
        if (kt < 15) {
            const float* a2 = sA + (kt + 1) * 64;
            av[nxt][0] = *(const float4*)(a2 + ac * 4);
            av[nxt][1] = *(const float4*)(a2 + 32 + ac * 4);
        }
        *(f16x4*)(As + wadr0) = cvt4(av[cur][0]);
        *(f16x4*)(As + wadr1) = cvt4(av[cur][1]);
        __syncthreads();
        #pragma unroll
        for (int ks = 0; ks < 2; ++ks) {
            int kc = ks * 4 + q;
            f16x8 af = *(const f16x8*)(As + arow_rd + ((kc ^ asw) * 8));
            #pragma unroll
            for (int c = 0; c < 4; ++c) {
                f16x8 b = *(const f16x8*)(Bs + (kc * 128 + wc * 64 + c * 16 + l15) * 8);
                acc[c] = __builtin_amdgcn_mfma_f32_16x16x32_f16(af, b, acc[c], 0, 0, 0);
            }
        }
    }
    #pragma unroll
    for (int c = 0; c < 4; ++c) {
        int n = wc * 64 + c * 16 + l15;
        float bv = bias[n];
        #pragma unroll
        for (int r = 0; r < 4; ++r) {
            int mm = m0 + wr * 16 + q * 4 + r;
            if (mm < M)
                C[(size_t)mm * 128 + n] =
                    __builtin_bit_cast(ushort_t, (_Float16)fmaxf(acc[c][r] + bv, 0.f));
        }
    }
}

// ---------------------------------------------------------------------------
// GEMM2 + fused alpha1: h1h(fp16) = h0h @ W1h, f16 MFMA.
// ---------------------------------------------------------------------------
__global__ __launch_bounds__(256) void kgemm_mfma2(const ushort_t* __restrict__ Ah,
                                                   const ushort_t* __restrict__ W1h,
                                                   const float* __restrict__ a_src,
                                                   const float* __restrict__ a_dst,
                                                   ushort_t* __restrict__ C,
                                                   float* __restrict__ as1,
                                                   float* __restrict__ ad1, int M) {
    __shared__ __align__(16) ushort_t Bs[16384];  // [kc16][n128][j8] fp16 = 32 KB
    int t = threadIdx.x;
    int wid = t >> 6, lane = t & 63;
    int q = lane >> 4, l15 = lane & 15;
    int g = blockIdx.y;
    int m0 = blockIdx.x * 64 + wid * 16;
    int m = m0 + l15;
    const ushort_t* arow = Ah + (size_t)(m < M ? m : 0) * 128;

    {   // stage W1h half (cols g*128..+127)
        #pragma unroll
        for (int i = 0; i < 8; ++i) {
            int j = i * 4 + wid;
            int kc = j >> 1, hk = j & 1;
            int ge = ((kc * 256) + g * 128 + hk * 64 + lane) * 8;
            int le = j * 512;
            __builtin_amdgcn_global_load_lds(AS_GLOBAL(W1h + ge), AS_SHARED(Bs + le), 16, 0, 0);
        }
    }
    f16x8 af[4];
    #pragma unroll
    for (int ks = 0; ks < 4; ++ks)
        af[ks] = *(const f16x8*)(arow + ks * 32 + q * 8);
    __syncthreads();

    f32x4 acc[8];
    #pragma unroll
    for (int c = 0; c < 8; ++c) acc[c] = (f32x4){0.f, 0.f, 0.f, 0.f};

    #pragma unroll
    for (int ks = 0; ks < 4; ++ks) {
        int kc = ks * 4 + q;
        #pragma unroll
        for (int c = 0; c < 8; ++c) {
            f16x8 b = *(const f16x8*)(Bs + (kc * 128 + c * 16 + l15) * 8);
            acc[c] = __builtin_amdgcn_mfma_f32_16x16x32_f16(af[ks], b, acc[c], 0, 0, 0);
        }
    }
    #pragma unroll
    for (int c = 0; c < 8; ++c) {
        int n = g * 128 + c * 16 + l15;
        #pragma unroll
        for (int r = 0; r < 4; ++r) {
            int mm = m0 + q * 4 + r;
            if (mm < M)
                C[(size_t)mm * 256 + n] = __builtin_bit_cast(ushort_t, (_Float16)acc[c][r]);
        }
    }
    float asv[4] = {0.f, 0.f, 0.f, 0.f};
    float adv[4] = {0.f, 0.f, 0.f, 0.f};
    #pragma unroll
    for (int c = 0; c < 8; ++c) {
        float sa = a_src[g * 128 + c * 16 + l15];
        float da = a_dst[g * 128 + c * 16 + l15];
        #pragma unroll
        for (int r = 0; r < 4; ++r) {
            asv[r] += acc[c][r] * sa;
            adv[r] += acc[c][r] * da;
        }
    }
    #pragma unroll
    for (int off = 1; off <= 8; off <<= 1) {
        #pragma unroll
        for (int r = 0; r < 4; ++r) {
            asv[r] += __shfl_xor(asv[r], off, 64);
            adv[r] += __shfl_xor(adv[r], off, 64);
        }
    }
    if (l15 == 0) {
        #pragma unroll
        for (int r = 0; r < 4; ++r) {
            int node = m0 + q * 4 + r;
            if (node < M) {
                as1[node * 2 + g] = asv[r];
                ad1[node * 2 + g] = adv[r];
            }
        }
    }
}

// ---------------------------------------------------------------------------
// Aggregation layer 1 + fused layer-2 linear + alpha2.
// ---------------------------------------------------------------------------
__global__ __launch_bounds__(128) void kagg1(const ushort_t* __restrict__ h1h,
                                             const float* __restrict__ as1,
                                             const float* __restrict__ ad1,
                                             const float* __restrict__ b1,
                                             const float* __restrict__ W2,
                                             const float* __restrict__ a_src2,
                                             const float* __restrict__ a_dst2,
                                             const int* __restrict__ row_ptr,
                                             const int* __restrict__ edge_src,
                                             float* __restrict__ h2,
                                             float* __restrict__ as2,
                                             float* __restrict__ ad2, int n) {
    __shared__ float w_lds[128];
    __shared__ int   s_lds[64];
    __shared__ float red[2][4];
    int node = blockIdx.x;
    int t = threadIdx.x;
    int wid = t >> 6;
    int beg = row_ptr[node], end = row_ptr[node + 1];
    int h_ch = t >> 6;
    float advv = ad1[node * 2 + (t & 1)];
    float acc0 = 0.f, acc1 = 0.f, ssum = 0.f;
    for (int base = beg; base < end; base += 64) {
        int cnt = min(64, end - base);
        int i = t >> 1, h = t & 1;
        if (i < cnt) {
            int s = edge_src[base + i];
            float e = as1[s * 2 + h] + advv;
            e = (e > 0.f) ? e : NEG_SLOPE * e;
            w_lds[i * 2 + h] = __expf(e);
            if (h == 0) s_lds[i] = s;
        }
        __syncthreads();
        #pragma unroll 4
        for (int i2 = 0; i2 < cnt; ++i2) {
            float wv = w_lds[i2 * 2 + h_ch];
            int s = s_lds[i2];
            unsigned p = *(const unsigned*)(h1h + (size_t)s * 256 + t * 2);
            _Float16 lo16 = __builtin_bit_cast(_Float16, (ushort_t)(p & 0xffffu));
            _Float16 hi16 = __builtin_bit_cast(_Float16, (ushort_t)(p >> 16));
            acc0 += wv * (float)lo16;
            acc1 += wv * (float)hi16;
            ssum += wv;
        }
        __syncthreads();
    }
    float inv = 1.f / (ssum + 1e-16f);
    float o0 = acc0 * inv + b1[t * 2];
    float o1 = acc1 * inv + b1[t * 2 + 1];
    o0 = (o0 > 0.f) ? o0 : (__expf(o0) - 1.f);
    o1 = (o1 > 0.f) ? o1 : (__expf(o1) - 1.f);
    float4 w0 = *(const float4*)(W2 + t * 8);
    float4 w1 = *(const float4*)(W2 + t * 8 + 4);
    float p0 = o0 * w0.x + o1 * w1.x;
    float p1 = o0 * w0.y + o1 * w1.y;
    float p2 = o0 * w0.z + o1 * w1.z;
    float p3 = o0 * w0.w + o1 * w1.w;
    #pragma unroll
    for (int off = 1; off < 64; off <<= 1) {
        p0 += __shfl_xor(p0, off, 64);
        p1 += __shfl_xor(p1, off, 64);
        p2 += __shfl_xor(p2, off, 64);
        p3 += __shfl_xor(p3, off, 64);
    }
    if ((t & 63) == 0) {
        red[wid][0] = p0; red[wid][1] = p1; red[wid][2] = p2; red[wid][3] = p3;
    }
    __syncthreads();
    if (t == 0) {
        float hv[4], s2 = 0.f, d2 = 0.f;
        #pragma unroll
        for (int j = 0; j < 4; ++j) {
            hv[j] = red[0][j] + red[1][j];
            h2[node * 4 + j] = hv[j];
            s2 += hv[j] * a_src2[j];
            d2 += hv[j] * a_dst2[j];
        }
        as2[node] = s2;
        ad2[node] = d2;
    }
}

// ---------------------------------------------------------------------------
// Aggregation layer 2 (1 head, C=4): wave per node, 16 edges in flight.
// ---------------------------------------------------------------------------
__global__ __launch_bounds__(256) void kagg2(const float* __restrict__ h2,
                                             const float* __restrict__ as2,
                                             const float* __restrict__ ad2,
                                             const float* __restrict__ b2,
                                             const int* __restrict__ row_ptr,
                                             const int* __restrict__ edge_src,
                                             float* __restrict__ out, int n) {
    int wid = threadIdx.x >> 6, lane = threadIdx.x & 63;
    int node = blockIdx.x * 4 + wid;
    if (node >= n) return;
    int beg = row_ptr[node], end = row_ptr[node + 1];
    int j = lane & 3, ig = lane >> 2;
    float adv = ad2[node];
    float acc = 0.f, ssum = 0.f;
    for (int p = beg + ig; p < end; p += 16) {
        int s = edge_src[p];
        float e = as2[s] + adv;
        e = (e > 0.f) ? e : NEG_SLOPE * e;
        float wv = __expf(e);
        acc += wv * h2[s * 4 + j];
        ssum += wv;
    }
    #pragma unroll
    for (int off = 32; off >= 4; off >>= 1) {
        acc += __shfl_down(acc, off);
        ssum += __shfl_down(ssum, off);
    }
    if (lane < 4) out[node * 4 + j] = acc / (ssum + 1e-16f) + b2[j];
}

// ---------------------------------------------------------------------------
extern "C" void kernel_launch(void* const* d_in, const int* in_sizes, int n_in,
                              void* d_out, int out_size, void* d_ws, size_t ws_size,
                              hipStream_t stream) {
    const float* x      = (const float*)d_in[0];
    const int*   ei     = (const int*)d_in[1];
    const float* W_pre  = (const float*)d_in[2];
    const float* b_pre  = (const float*)d_in[3];
    const float* W1     = (const float*)d_in[4];
    const float* a_src1 = (const float*)d_in[5];
    const float* a_dst1 = (const float*)d_in[6];
    const float* b1     = (const float*)d_in[7];
    const float* W2     = (const float*)d_in[8];
    const float* a_src2 = (const float*)d_in[9];
    const float* a_dst2 = (const float*)d_in[10];
    const float* b2     = (const float*)d_in[11];
    float* out = (float*)d_out;

    const int DIN = 1024;
    const int E = in_sizes[1] / 2;
    const int N = in_sizes[0] / DIN;

    const int* esrc = ei;
    const int* edst = ei + E;

    char* ws = (char*)d_ws;
    size_t off = 0;
    ushort_t* h1h = (ushort_t*)(ws + off); off += (size_t)N * 256 * 2;
    ushort_t* h0h = (ushort_t*)(ws + off); off += (size_t)N * 128 * 2;
    float* as1 = (float*)(ws + off);  off += (size_t)N * 2 * 4;
    float* ad1 = (float*)(ws + off);  off += (size_t)N * 2 * 4;
    float* h2  = (float*)(ws + off);  off += (size_t)N * 4 * 4;
    float* as2 = (float*)(ws + off);  off += (size_t)N * 4;
    float* ad2 = (float*)(ws + off);  off += (size_t)N * 4;
    int* row_ptr = (int*)(ws + off);  off += ((size_t)N + 16) * 4;
    int* cursor  = (int*)(ws + off);  off += (size_t)N * 4;
    int* counts  = (int*)(ws + off);  off += (size_t)N * 4;
    int* bsum    = (int*)(ws + off);  off += 64 * 4;
    int* boff    = (int*)(ws + off);  off += 64 * 4;
    int* edge_src = (int*)(ws + off); off += (size_t)(E + N) * 4;
    ushort_t* PreF = (ushort_t*)(ws + off); off += 1024 * 128 * 2;
    ushort_t* W1h  = (ushort_t*)(ws + off); off += 128 * 256 * 2;

    int G = (N + 1023) / 1024;

    kprep<<<640, 256, 0, stream>>>(W_pre, W1, PreF, W1h);
    hipMemsetAsync(counts, 0, (size_t)N * 4, stream);
    khist<<<(E + 255) / 256, 256, 0, stream>>>(edst, E, counts);
    kscan_part<<<G, 1024, 0, stream>>>(counts, row_ptr, bsum, N);
    kscan_tops<<<1, 64, 0, stream>>>(bsum, boff, row_ptr, G, N);
    kscan_add<<<(N + 255) / 256, 256, 0, stream>>>(row_ptr, boff, cursor, N);
    kfill<<<(E + N + 255) / 256, 256, 0, stream>>>(esrc, edst, E, N, cursor, edge_src);

    int Mb32 = (N + 31) / 32;
    kgemm_mfma1<<<Mb32, 256, 0, stream>>>(x, PreF, b_pre, h0h, N);
    {
        int Mb = (N + 63) / 64;
        dim3 grid(Mb, 2);
        kgemm_mfma2<<<grid, 256, 0, stream>>>(h0h, W1h, a_src1, a_dst1, h1h, as1, ad1, N);
    }
    kagg1<<<N, 128, 0, stream>>>(h1h, as1, ad1, b1, W2, a_src2, a_dst2,
                                 row_ptr, edge_src, h2, as2, ad2, N);
    kagg2<<<(N + 3) / 4, 256, 0, stream>>>(h2, as2, ad2, b2, row_ptr, edge_src, out, N);
}